// Round 1
// baseline (189.261 us; speedup 1.0000x reference)
//
#include <hip/hip_runtime.h>
#include <hip/hip_bf16.h>

// ---------------------------------------------------------------------------
// InferCellV2 R7: R6 + T14 async source-switch staging + vectorized pre-store.
// R6 lesson: barrier-free 9-tap source loop works, but every source switch is
// a fully serial global_load_lds stage (~3-4us of dead matrix pipe per switch,
// 1 block/CU so nothing hides it). R7: prefetch source s+1's A+B into VGPRs
// (19 x dwordx4 = 76 regs) at the TOP of source s's compute - HBM latency
// hides under ~12k cyc of MFMA - then commit with ds_write_b128 after the
// read-done barrier (~0.7us instead of 3-4us). sched_barrier(0) after the
// load issue stops LLVM sinking the loads to the commit point (guide rule:
// loads sink under register pressure, defeating the overlap).
// Also: relu-pad store vectorized to one 16B chunk store/thread (was 8 scalar
// bf16 stores); s_setprio(1) around the MFMA cluster (T5 - waves free-run
// across taps here, so there is role diversity, unlike lockstep GEMM).
// Block 512 thr / 8 waves / 16 out rows; grid 256 = 1 block/CU, single round.
// Layouts (verified conflict-free in R3, SQ_LDS_BANK_CONFLICT=0):
//   activations: zero-padded NHWC bf16 [B][34][34][64], chunk cb of pixel p
//     at p*128 + ((cb^(p&7))*16);  weights wt[l][tap][o][i], chunk i>>3 of
//     row o at slot (i>>3)^(o&7). Staging = linear 16B chunks (chunk idx =
//     it*512+tid for both the gld16 path and the reg-commit path).
// Wave tile 64px x 64oc = 4x4 MFMA 16x16x32, 64 acc VGPRs.
// ---------------------------------------------------------------------------

typedef __bf16 bf16x8 __attribute__((ext_vector_type(8)));
typedef float floatx4 __attribute__((ext_vector_type(4)));
typedef unsigned int uint32;

#define PADW 34
#define PIMG (PADW * PADW)
#define ROWB (PADW * 64 * 2)        // 4352 B per padded NHWC row
#define A_LDS (18 * ROWB)           // 78336 (16 out rows + 2 halo)
#define A_CHUNKS (A_LDS / 16)       // 4896 = 9*512 + 288
#define A_TAIL (A_CHUNKS - 9 * 512) // 288
#define TAPB (64 * 64 * 2)          // 8192 B per weight tap
#define B_LDS (9 * TAPB)            // 73728
#define B_CHUNKS (B_LDS / 16)       // 4608 = 9*512
#define SMEM_BYTES (A_LDS + B_LDS)  // 152064

__device__ __forceinline__ void gld16(const char* g, char* l) {
    __builtin_amdgcn_global_load_lds(
        (const __attribute__((address_space(1))) uint32*)g,
        (__attribute__((address_space(3))) uint32*)l, 16, 0, 0);
}

// ---------------- fused pre-pass: prep_weights + zero_halo + relu_pad -------
__global__ __launch_bounds__(256) void pre_kernel(
    const float* __restrict__ in, const float* __restrict__ a1,
    const float* __restrict__ a2, const float* __restrict__ W,
    __hip_bfloat16* __restrict__ wt, __hip_bfloat16* __restrict__ r0,
    __hip_bfloat16* __restrict__ r1, __hip_bfloat16* __restrict__ r2) {
    __shared__ float tile[32][65];
    int blk = blockIdx.x;
    int tid = threadIdx.x;

    if (blk < 864) {                 // ---- weights: fold scale + swizzle
        int idx = blk * 256 + tid;   // 6*9*64*64 = 221184 exact
        int i = idx & 63;
        int o = (idx >> 6) & 63;
        int rest = idx >> 12;
        int t = rest % 9;
        int l = rest / 9;
        int ji = i >> 3, jo = o >> 3;
        float ain = 0.f, aout = 0.f;
#pragma unroll
        for (int j = 0; j < 8; ++j) {
            ain  += (j >= ji) ? a1[j] : 0.f;
            aout += (j >= jo) ? a2[j] : 0.f;
        }
        float v = W[(size_t)((l * 64 + o) * 64 + i) * 9 + t] * ain * aout;
        size_t e = (size_t)(l * 9 + t) * 4096 + o * 64 +
                   ((((i >> 3) ^ (o & 7)) << 3) + (i & 7));
        wt[e] = __float2bfloat16(v);
    } else if (blk < 992) {          // ---- zero halo ring, image b
        int b = blk - 864;
        __hip_bfloat16* bufs[3] = {r0, r1, r2};
#pragma unroll
        for (int f = 0; f < 3; ++f) {
            uint32* buf = (uint32*)(bufs[f] + (size_t)b * PIMG * 64);
            for (int idx = tid; idx < 132 * 32; idx += 256) {
                int slot = idx >> 5, u = idx & 31;
                int yy, xx;
                if (slot < 34)      { yy = 0;  xx = slot; }
                else if (slot < 68) { yy = 33; xx = slot - 34; }
                else { int s2 = slot - 68; yy = 1 + (s2 >> 1); xx = (s2 & 1) * 33; }
                buf[(size_t)(yy * PADW + xx) * 32 + u] = 0u;
            }
        }
    } else {                         // ---- relu(x) -> padded swizzled NHWC
        int rb = blk - 992;
        int b = rb >> 5, y = rb & 31;
        int x = tid & 31, c0 = tid >> 5;
        const float* ip = in + ((size_t)b * 64 * 32 + y) * 32 + x;
#pragma unroll
        for (int cc = 0; cc < 8; ++cc) {
            int c = cc * 8 + c0;
            tile[x][c] = fmaxf(ip[(size_t)c * 1024], 0.f);
        }
        __syncthreads();
        // one 16B chunk store per thread (was 8 scalar bf16 stores): thread =
        // (pixel xq, chunk j); chunk j of pixel p lives at p*128 + (j^(p&7))*16.
        int j = tid & 7, xq = tid >> 3;
        int p = (b * PADW + y + 1) * PADW + 1 + xq;
        alignas(16) __hip_bfloat16 hv[8];
#pragma unroll
        for (int k = 0; k < 8; ++k)
            hv[k] = __float2bfloat16(tile[xq][j * 8 + k]);
        *(uint4*)((char*)r0 + (size_t)p * 128 + ((j ^ (p & 7)) << 4)) =
            *(const uint4*)hv;
    }
}

// ---------------- conv stage: barrier-free within each source ---------------
// Block: image b = blk>>1, strip y0 = (blk&1)*16. Wave wv: rows y0+2wv,+1.
// A-frag: l15 = px, quad*8+q*32 = in-ch. B-frag: l15 = oc. C/D: M=quad*4+r.
template <int NSRC, bool FINAL>
__global__ __launch_bounds__(512, 2) void conv_stage(
    const __hip_bfloat16* __restrict__ s0,
    const __hip_bfloat16* __restrict__ s1,
    const __hip_bfloat16* __restrict__ s2,
    const __hip_bfloat16* __restrict__ wt,
    void* __restrict__ dstv, int l0) {
    extern __shared__ char smem[];               // A_LDS + B_LDS = 152064 B
    char* smemB = smem + A_LDS;
    int tid = threadIdx.x;
    int wv = tid >> 6, lane = tid & 63;
    int quad = lane >> 4, l15 = lane & 15;
    int blk = blockIdx.x;
    int b = blk >> 1, y0 = (blk & 1) << 4;

    const char* srcs[3] = {(const char*)s0, (const char*)s1, (const char*)s2};
    const char* gW = (const char*)wt + (size_t)l0 * 9 * (size_t)TAPB;

    auto stage_A = [&](int s) {      // 18 padded rows, linear 16B DMA copy
        const char* gA = srcs[s] + (size_t)(b * PADW + y0) * PADW * 128;
#pragma unroll
        for (int it = 0; it < 10; ++it) {
            int c = it * 512 + tid;
            if (it < 9 || tid < A_TAIL)
                gld16(gA + (size_t)c * 16, smem + (it * 512 + wv * 64) * 16);
        }
    };
    auto stage_B = [&](int s) {      // 9 taps of src s, linear 16B DMA copy
        const char* gB = gW + (size_t)s * 9 * TAPB;
#pragma unroll
        for (int it = 0; it < 9; ++it) {
            int c = it * 512 + tid;
            gld16(gB + (size_t)c * 16, smemB + (it * 512 + wv * 64) * 16);
        }
    };

    // T14 register prefetch of the NEXT source (A: 10 chunks, B: 9 chunks).
    uint4 pfA[10], pfB[9];
    auto prefetch = [&](int s) {
        const char* gA = srcs[s] + (size_t)(b * PADW + y0) * PADW * 128;
#pragma unroll
        for (int it = 0; it < 10; ++it)
            if (it < 9 || tid < A_TAIL)
                pfA[it] = *(const uint4*)(gA + (size_t)(it * 512 + tid) * 16);
        const char* gB = gW + (size_t)s * 9 * TAPB;
#pragma unroll
        for (int it = 0; it < 9; ++it)
            pfB[it] = *(const uint4*)(gB + (size_t)(it * 512 + tid) * 16);
    };
    auto commit = [&]() {            // same chunk->LDS mapping as gld16 path
#pragma unroll
        for (int it = 0; it < 10; ++it)
            if (it < 9 || tid < A_TAIL)
                *(uint4*)(smem + (size_t)(it * 512 + tid) * 16) = pfA[it];
#pragma unroll
        for (int it = 0; it < 9; ++it)
            *(uint4*)(smemB + (size_t)(it * 512 + tid) * 16) = pfB[it];
    };

    floatx4 acc[4][4];
#pragma unroll
    for (int m = 0; m < 4; ++m)
#pragma unroll
        for (int n = 0; n < 4; ++n) acc[m][n] = (floatx4){0.f, 0.f, 0.f, 0.f};

    stage_A(0);
    stage_B(0);
    __syncthreads();                 // src0 operands resident

#pragma unroll 1
    for (int s = 0; s < NSRC; ++s) {
        if (s + 1 < NSRC) {
            prefetch(s + 1);         // issue loads; complete under MFMA below
            __builtin_amdgcn_sched_barrier(0);  // don't sink loads to commit
        }
#pragma unroll
        for (int tl = 0; tl < 9; ++tl) {
            const int ky = tl / 3, kx = tl % 3;
#pragma unroll
            for (int q = 0; q < 2; ++q) {
                bf16x8 Af[4], Bf[4];
#pragma unroll
                for (int m = 0; m < 4; ++m) {
                    int arow = 2 * wv + (m >> 1) + ky;      // LDS row 0..17
                    int apx  = ((m & 1) << 4) + l15 + kx;   // 0..33
                    int R = b * PADW + y0 + arow;           // global padded row
                    int slot = ((q << 2) + quad) ^ ((2 * R + apx) & 7);
                    Af[m] = *(const bf16x8*)(smem + arow * ROWB +
                                             apx * 128 + slot * 16);
                }
#pragma unroll
                for (int n = 0; n < 4; ++n) {
                    int o = (n << 4) + l15;
                    int slot = ((q << 2) + quad) ^ (l15 & 7);
                    Bf[n] = *(const bf16x8*)(smemB + tl * TAPB +
                                             o * 128 + slot * 16);
                }
                __builtin_amdgcn_s_setprio(1);   // T5: favor the MFMA cluster
#pragma unroll
                for (int m = 0; m < 4; ++m)
#pragma unroll
                    for (int n = 0; n < 4; ++n)
                        acc[m][n] = __builtin_amdgcn_mfma_f32_16x16x32_bf16(
                            Af[m], Bf[n], acc[m][n], 0, 0, 0);
                __builtin_amdgcn_s_setprio(0);
            }
        }
        if (s + 1 < NSRC) {          // source switch: loads already in flight
            __syncthreads();         // all waves done reading src s operands
            commit();                // 19 x ds_write_b128 (~0.7us, was 3-4us)
            __syncthreads();         // writes visible to all waves
        }
    }

    // Epilogue. M(pixel) = quad*4+r (+16 for odd m-tile), N(oc) = n*16+l15.
    if (FINAL) {
        float* out = (float*)dstv;   // fp32 NCHW [128][64][32][32]
#pragma unroll
        for (int m = 0; m < 4; ++m) {
            int row = y0 + 2 * wv + (m >> 1);
#pragma unroll
            for (int n = 0; n < 4; ++n) {
                int o = (n << 4) + l15;
                *(floatx4*)(out + (((size_t)b * 64 + o) * 32 + row) * 32 +
                            ((m & 1) << 4) + (quad << 2)) = acc[m][n];
            }
        }
    } else {
        __hip_bfloat16* out = (__hip_bfloat16*)dstv;  // relu -> swizzled NHWC
#pragma unroll
        for (int m = 0; m < 4; ++m) {
            int row = y0 + 2 * wv + (m >> 1);
#pragma unroll
            for (int n = 0; n < 4; ++n) {
                int o = (n << 4) + l15;
#pragma unroll
                for (int r = 0; r < 4; ++r) {
                    int x = ((m & 1) << 4) + (quad << 2) + r;
                    int p = (b * PADW + row + 1) * PADW + x + 1;
                    float v = fmaxf(acc[m][n][r], 0.f);
                    size_t e = (size_t)p * 64 +
                               ((((o >> 3) ^ (p & 7)) << 3) + (o & 7));
                    out[e] = __float2bfloat16(v);
                }
            }
        }
    }
}

// ---------------------------------------------------------------------------
extern "C" void kernel_launch(void* const* d_in, const int* in_sizes, int n_in,
                              void* d_out, int out_size, void* d_ws,
                              size_t ws_size, hipStream_t stream) {
    const float* inputs  = (const float*)d_in[0];
    const float* alphas1 = (const float*)d_in[1];
    const float* alphas2 = (const float*)d_in[2];
    const float* W       = (const float*)d_in[3];
    char* ws = (char*)d_ws;

    __hip_bfloat16* wt = (__hip_bfloat16*)(ws);                     // 442 KB
    __hip_bfloat16* r0 = (__hip_bfloat16*)(ws + ((size_t)1 << 20)); // 18.9 MB
    __hip_bfloat16* r1 = (__hip_bfloat16*)(ws + ((size_t)20 << 20));
    __hip_bfloat16* r2 = (__hip_bfloat16*)(ws + ((size_t)40 << 20));
    float* out = (float*)d_out;

    // Opt-in to >64KB dynamic LDS (idempotent; harmless under graph capture).
    (void)hipFuncSetAttribute((const void*)conv_stage<1, false>,
                              hipFuncAttributeMaxDynamicSharedMemorySize,
                              SMEM_BYTES);
    (void)hipFuncSetAttribute((const void*)conv_stage<2, false>,
                              hipFuncAttributeMaxDynamicSharedMemorySize,
                              SMEM_BYTES);
    (void)hipFuncSetAttribute((const void*)conv_stage<3, true>,
                              hipFuncAttributeMaxDynamicSharedMemorySize,
                              SMEM_BYTES);

    pre_kernel<<<864 + 128 + 4096, 256, 0, stream>>>(inputs, alphas1, alphas2,
                                                     W, wt, r0, r1, r2);
    conv_stage<1, false><<<256, 512, SMEM_BYTES, stream>>>(r0, r1, r2, wt,
                                                           (void*)r1, 0);
    conv_stage<2, false><<<256, 512, SMEM_BYTES, stream>>>(r0, r1, r2, wt,
                                                           (void*)r2, 1);
    conv_stage<3, true ><<<256, 512, SMEM_BYTES, stream>>>(r0, r1, r2, wt,
                                                           (void*)out, 3);
}

// Round 2
// 154.166 us; speedup vs baseline: 1.2276x; 1.2276x over previous
//
#include <hip/hip_runtime.h>
#include <hip/hip_bf16.h>

// ---------------------------------------------------------------------------
// InferCellV2 R8: 2 blocks/CU + LDS ping-pong weight staging.
// R7 post-mortem: T14 register prefetch (76 VGPRs live across barriers+MFMA
// region) spilled to scratch (VGPR_Count=100, FETCH 68MB, WRITE 113MB, +38us/
// stage). Reverted. R7's counters exposed the real limit: 152KB LDS -> 1
// block/CU -> 2 waves/SIMD in ONE barrier domain; MfmaUtil ~18-35% vs a 14us
// MFMA floor for conv<3>. Nothing covers ds_read latency / stage / epilogue.
// R8: 256-thr blocks, 8-row strips (A = 10 rows = 43.5KB), B split into
// 2-tap groups ping-ponged between two 16KB LDS buffers: next group's
// global_load_lds issues BEFORE current group's MFMAs; the barrier's
// vmcnt-drain (compiler emits vmcnt(0) before s_barrier) completes it exactly
// when needed. 1-deep pipeline, zero VGPR cost. LDS 76288B -> 2 blocks/CU =
// two independent barrier domains covering each other's stalls (m114).
// Source switch serial-stages only A (~0.4us, covered by sibling block).
// Layouts unchanged from R3/R6 (verified conflict-free):
//   activations: zero-padded NHWC bf16 [B][34][34][64], chunk cb of pixel p
//     at p*128 + ((cb^(p&7))*16);  weights wt[l][tap][o][i], chunk i>>3 of
//     row o at slot (i>>3)^(o&7). Staging = linear 16B chunks.
// Wave tile 64px x 64oc = 4x4 MFMA 16x16x32, 64 acc VGPRs (as R6).
// ---------------------------------------------------------------------------

typedef __bf16 bf16x8 __attribute__((ext_vector_type(8)));
typedef float floatx4 __attribute__((ext_vector_type(4)));
typedef unsigned int uint32;

#define PADW 34
#define PIMG (PADW * PADW)
#define ROWB (PADW * 64 * 2)        // 4352 B per padded NHWC row
#define A_LDS (10 * ROWB)           // 43520 (8 out rows + 2 halo)
#define A_CHUNKS (A_LDS / 16)       // 2720 = 10*256 + 160
#define A_TAIL (A_CHUNKS - 10 * 256)// 160
#define TAPB (64 * 64 * 2)          // 8192 B per weight tap
#define GRPB (2 * TAPB)             // 16384 B per 2-tap group buffer
#define SMEM_BYTES (A_LDS + 2 * GRPB) // 76288 -> 2 blocks/CU (152.6KB/160KB)

__device__ __forceinline__ void gld16(const char* g, char* l) {
    __builtin_amdgcn_global_load_lds(
        (const __attribute__((address_space(1))) uint32*)g,
        (__attribute__((address_space(3))) uint32*)l, 16, 0, 0);
}

// ---------------- fused pre-pass: prep_weights + zero_halo + relu_pad -------
__global__ __launch_bounds__(256) void pre_kernel(
    const float* __restrict__ in, const float* __restrict__ a1,
    const float* __restrict__ a2, const float* __restrict__ W,
    __hip_bfloat16* __restrict__ wt, __hip_bfloat16* __restrict__ r0,
    __hip_bfloat16* __restrict__ r1, __hip_bfloat16* __restrict__ r2) {
    __shared__ float tile[32][65];
    int blk = blockIdx.x;
    int tid = threadIdx.x;

    if (blk < 864) {                 // ---- weights: fold scale + swizzle
        int idx = blk * 256 + tid;   // 6*9*64*64 = 221184 exact
        int i = idx & 63;
        int o = (idx >> 6) & 63;
        int rest = idx >> 12;
        int t = rest % 9;
        int l = rest / 9;
        int ji = i >> 3, jo = o >> 3;
        float ain = 0.f, aout = 0.f;
#pragma unroll
        for (int j = 0; j < 8; ++j) {
            ain  += (j >= ji) ? a1[j] : 0.f;
            aout += (j >= jo) ? a2[j] : 0.f;
        }
        float v = W[(size_t)((l * 64 + o) * 64 + i) * 9 + t] * ain * aout;
        size_t e = (size_t)(l * 9 + t) * 4096 + o * 64 +
                   ((((i >> 3) ^ (o & 7)) << 3) + (i & 7));
        wt[e] = __float2bfloat16(v);
    } else if (blk < 992) {          // ---- zero halo ring, image b
        int b = blk - 864;
        __hip_bfloat16* bufs[3] = {r0, r1, r2};
#pragma unroll
        for (int f = 0; f < 3; ++f) {
            uint32* buf = (uint32*)(bufs[f] + (size_t)b * PIMG * 64);
            for (int idx = tid; idx < 132 * 32; idx += 256) {
                int slot = idx >> 5, u = idx & 31;
                int yy, xx;
                if (slot < 34)      { yy = 0;  xx = slot; }
                else if (slot < 68) { yy = 33; xx = slot - 34; }
                else { int s2 = slot - 68; yy = 1 + (s2 >> 1); xx = (s2 & 1) * 33; }
                buf[(size_t)(yy * PADW + xx) * 32 + u] = 0u;
            }
        }
    } else {                         // ---- relu(x) -> padded swizzled NHWC
        int rb = blk - 992;
        int b = rb >> 5, y = rb & 31;
        int x = tid & 31, c0 = tid >> 5;
        const float* ip = in + ((size_t)b * 64 * 32 + y) * 32 + x;
#pragma unroll
        for (int cc = 0; cc < 8; ++cc) {
            int c = cc * 8 + c0;
            tile[x][c] = fmaxf(ip[(size_t)c * 1024], 0.f);
        }
        __syncthreads();
        // one 16B chunk store per thread: thread = (pixel xq, chunk j);
        // chunk j of pixel p lives at p*128 + (j^(p&7))*16.
        int j = tid & 7, xq = tid >> 3;
        int p = (b * PADW + y + 1) * PADW + 1 + xq;
        alignas(16) __hip_bfloat16 hv[8];
#pragma unroll
        for (int k = 0; k < 8; ++k)
            hv[k] = __float2bfloat16(tile[xq][j * 8 + k]);
        *(uint4*)((char*)r0 + (size_t)p * 128 + ((j ^ (p & 7)) << 4)) =
            *(const uint4*)hv;
    }
}

// ---------------- conv stage: ping-pong B groups, 2 blocks/CU --------------
// Block: image b = blk>>2, strip y0 = (blk&3)*8. Wave wv (0..3): rows
// y0+2wv, y0+2wv+1.  A-frag: l15 = px, quad*8+q*32 = in-ch. B-frag: l15 = oc.
// B groups per source: taps {0,1}{2,3}{4,5}{6,7}{8}, buffer = (s+g)&1.
template <int NSRC, bool FINAL>
__global__ __launch_bounds__(256, 2) void conv_stage(
    const __hip_bfloat16* __restrict__ s0,
    const __hip_bfloat16* __restrict__ s1,
    const __hip_bfloat16* __restrict__ s2,
    const __hip_bfloat16* __restrict__ wt,
    void* __restrict__ dstv, int l0) {
    extern __shared__ char smem[];               // A_LDS + 2*GRPB = 76288 B
    char* smemB = smem + A_LDS;
    int tid = threadIdx.x;
    int wv = tid >> 6, lane = tid & 63;
    int quad = lane >> 4, l15 = lane & 15;
    int blk = blockIdx.x;
    int b = blk >> 2, y0 = (blk & 3) << 3;

    const char* srcs[3] = {(const char*)s0, (const char*)s1, (const char*)s2};
    const char* gW = (const char*)wt + (size_t)l0 * 9 * (size_t)TAPB;

    auto stage_A = [&](int s) {      // 10 padded rows, linear 16B DMA copy
        const char* gA = srcs[s] + (size_t)(b * PADW + y0) * PADW * 128;
#pragma unroll
        for (int it = 0; it < 11; ++it) {
            int c = it * 256 + tid;
            if (it < 10 || tid < A_TAIL)
                gld16(gA + (size_t)c * 16, smem + (it * 256 + wv * 64) * 16);
        }
    };
    // nt taps starting at tap0 of source s -> buffer dst (16B linear chunks)
    auto stage_B = [&](int s, int tap0, int nt, char* dst) {
#pragma unroll
        for (int it = 0; it < 2 * nt; ++it) {
            const char* gB = gW + ((size_t)s * 9 + tap0) * TAPB;
            gld16(gB + (size_t)(it * 256 + tid) * 16,
                  dst + (it * 256 + wv * 64) * 16);
        }
    };

    floatx4 acc[4][4];
#pragma unroll
    for (int m = 0; m < 4; ++m)
#pragma unroll
        for (int n = 0; n < 4; ++n) acc[m][n] = (floatx4){0.f, 0.f, 0.f, 0.f};

    stage_A(0);
    stage_B(0, 0, 2, smemB);         // group 0 of src 0 -> buf 0
    __syncthreads();                 // initial operands resident

#pragma unroll 1
    for (int s = 0; s < NSRC; ++s) {
        int sb = s & 1;              // buffer parity of (s, g=0)
#pragma unroll
        for (int g = 0; g < 5; ++g) {
            const int t0 = 2 * g;
            const int GT = (g == 4) ? 1 : 2;
            char* Bcur = smemB + (((g & 1) ? sb ^ 1 : sb) ? GRPB : 0);
            char* Bnxt = smemB + (((g & 1) ? sb ^ 1 : sb) ? 0 : GRPB);
            // issue next group's staging; completes at the barrier below
            if (g < 4) {
                const int nt0 = (g + 1 == 4) ? 1 : 2;
                stage_B(s, 2 * (g + 1), nt0, Bnxt);
            } else if (s + 1 < NSRC) {
                stage_B(s + 1, 0, 2, Bnxt);
            }
            __builtin_amdgcn_sched_barrier(0);   // keep issue before compute
#pragma unroll
            for (int tt = 0; tt < GT; ++tt) {
                const int tl = t0 + tt, ky = tl / 3, kx = tl % 3;
#pragma unroll
                for (int q = 0; q < 2; ++q) {
                    bf16x8 Af[4], Bf[4];
#pragma unroll
                    for (int m = 0; m < 4; ++m) {
                        int arow = 2 * wv + (m >> 1) + ky;    // LDS row 0..9
                        int apx  = ((m & 1) << 4) + l15 + kx; // 0..33
                        int R = b * PADW + y0 + arow;         // global pad row
                        int slot = ((q << 2) + quad) ^ ((2 * R + apx) & 7);
                        Af[m] = *(const bf16x8*)(smem + arow * ROWB +
                                                 apx * 128 + slot * 16);
                    }
#pragma unroll
                    for (int n = 0; n < 4; ++n) {
                        int o = (n << 4) + l15;
                        int slot = ((q << 2) + quad) ^ (l15 & 7);
                        Bf[n] = *(const bf16x8*)(Bcur + tt * TAPB +
                                                 o * 128 + slot * 16);
                    }
                    __builtin_amdgcn_s_setprio(1);
#pragma unroll
                    for (int m = 0; m < 4; ++m)
#pragma unroll
                        for (int n = 0; n < 4; ++n)
                            acc[m][n] =
                                __builtin_amdgcn_mfma_f32_16x16x32_bf16(
                                    Af[m], Bf[n], acc[m][n], 0, 0, 0);
                    __builtin_amdgcn_s_setprio(0);
                }
            }
            if (g < 4 || s + 1 < NSRC)
                __syncthreads();     // drains vmcnt -> next group resident
            if (g == 4 && s + 1 < NSRC) {
                stage_A(s + 1);      // serial A switch (~0.4us, sibling
                __syncthreads();     //  block on this CU covers it)
            }
        }
    }

    // Epilogue. M(pixel) = quad*4+r (+16 for odd m-tile), N(oc) = n*16+l15.
    if (FINAL) {
        float* out = (float*)dstv;   // fp32 NCHW [128][64][32][32]
#pragma unroll
        for (int m = 0; m < 4; ++m) {
            int row = y0 + 2 * wv + (m >> 1);
#pragma unroll
            for (int n = 0; n < 4; ++n) {
                int o = (n << 4) + l15;
                *(floatx4*)(out + (((size_t)b * 64 + o) * 32 + row) * 32 +
                            ((m & 1) << 4) + (quad << 2)) = acc[m][n];
            }
        }
    } else {
        __hip_bfloat16* out = (__hip_bfloat16*)dstv;  // relu -> swizzled NHWC
#pragma unroll
        for (int m = 0; m < 4; ++m) {
            int row = y0 + 2 * wv + (m >> 1);
#pragma unroll
            for (int n = 0; n < 4; ++n) {
                int o = (n << 4) + l15;
#pragma unroll
                for (int r = 0; r < 4; ++r) {
                    int x = ((m & 1) << 4) + (quad << 2) + r;
                    int p = (b * PADW + row + 1) * PADW + x + 1;
                    float v = fmaxf(acc[m][n][r], 0.f);
                    size_t e = (size_t)p * 64 +
                               ((((o >> 3) ^ (p & 7)) << 3) + (o & 7));
                    out[e] = __float2bfloat16(v);
                }
            }
        }
    }
}

// ---------------------------------------------------------------------------
extern "C" void kernel_launch(void* const* d_in, const int* in_sizes, int n_in,
                              void* d_out, int out_size, void* d_ws,
                              size_t ws_size, hipStream_t stream) {
    const float* inputs  = (const float*)d_in[0];
    const float* alphas1 = (const float*)d_in[1];
    const float* alphas2 = (const float*)d_in[2];
    const float* W       = (const float*)d_in[3];
    char* ws = (char*)d_ws;

    __hip_bfloat16* wt = (__hip_bfloat16*)(ws);                     // 442 KB
    __hip_bfloat16* r0 = (__hip_bfloat16*)(ws + ((size_t)1 << 20)); // 18.9 MB
    __hip_bfloat16* r1 = (__hip_bfloat16*)(ws + ((size_t)20 << 20));
    __hip_bfloat16* r2 = (__hip_bfloat16*)(ws + ((size_t)40 << 20));
    float* out = (float*)d_out;

    // Opt-in to >64KB dynamic LDS (idempotent; harmless under graph capture).
    (void)hipFuncSetAttribute((const void*)conv_stage<1, false>,
                              hipFuncAttributeMaxDynamicSharedMemorySize,
                              SMEM_BYTES);
    (void)hipFuncSetAttribute((const void*)conv_stage<2, false>,
                              hipFuncAttributeMaxDynamicSharedMemorySize,
                              SMEM_BYTES);
    (void)hipFuncSetAttribute((const void*)conv_stage<3, true>,
                              hipFuncAttributeMaxDynamicSharedMemorySize,
                              SMEM_BYTES);

    pre_kernel<<<864 + 128 + 4096, 256, 0, stream>>>(inputs, alphas1, alphas2,
                                                     W, wt, r0, r1, r2);
    conv_stage<1, false><<<512, 256, SMEM_BYTES, stream>>>(r0, r1, r2, wt,
                                                           (void*)r1, 0);
    conv_stage<2, false><<<512, 256, SMEM_BYTES, stream>>>(r0, r1, r2, wt,
                                                           (void*)r2, 1);
    conv_stage<3, true ><<<512, 256, SMEM_BYTES, stream>>>(r0, r1, r2, wt,
                                                           (void*)out, 3);
}